// Round 11
// baseline (447.811 us; speedup 1.0000x reference)
//
#include <hip/hip_runtime.h>
#include <hip/hip_bf16.h>
#include <cstdint>
#include <cstddef>

#define H 1024
#define V 50257
#define B 64
#define T 512

typedef __attribute__((ext_vector_type(8))) short bf16x8;
typedef __attribute__((ext_vector_type(4))) float f32x4;

__device__ __forceinline__ float sigmoidf_(float x) { return 1.0f / (1.0f + expf(-x)); }

__device__ __forceinline__ unsigned short f2bf_rn(float x) {
    __hip_bfloat16 h = __float2bfloat16(x);
    return __builtin_bit_cast(unsigned short, h);
}

__device__ __forceinline__ void gl_lds16(const float* g, float* l) {
    __builtin_amdgcn_global_load_lds(
        (const __attribute__((address_space(1))) unsigned*)g,
        (__attribute__((address_space(3))) unsigned*)l, 16, 0, 0);
}

__device__ __forceinline__ void wait_vm8() {
    asm volatile("s_waitcnt vmcnt(8)" ::: "memory");
    __builtin_amdgcn_sched_barrier(0);
}
__device__ __forceinline__ void wait_vm0() {
    asm volatile("s_waitcnt vmcnt(0)" ::: "memory");
    __builtin_amdgcn_sched_barrier(0);
}
__device__ __forceinline__ void lds_war_guard() {
    asm volatile("s_waitcnt lgkmcnt(0)" ::: "memory");
    __builtin_amdgcn_sched_barrier(0);
}

// ---------------------------------------------------------------------------
// Gate GEMMs (round-9 verbatim): z=0: Pgi = bf16(emb[seq]) @ Wih^T ;
// z=1: Pgh = bf16(h0) @ Whh^T.  Barrier-free + 2-ahead vmcnt.
__global__ __launch_bounds__(256) void k_gates(const int* __restrict__ seq,
                                               const float* __restrict__ emb,
                                               const float* __restrict__ h0,
                                               const float* __restrict__ Wih,
                                               const float* __restrict__ Whh,
                                               float* __restrict__ Pgi,
                                               float* __restrict__ Pgh) {
    __shared__ __align__(16) float Bs[2][128 * 64];
    const int z = blockIdx.z;
    const float* Bm = z ? Whh : Wih;
    float* C = (z ? Pgh : Pgi) + (size_t)blockIdx.y * 64 * (3 * H);
    const int t = threadIdx.x;
    const int w = t >> 6, lane = t & 63;
    const int li = lane & 15, qu = lane >> 4;
    const int n0 = blockIdx.x * 128;
    const int k0 = blockIdx.y * 256;
    const int N = 3 * H;

    const float* Arow[4];
#pragma unroll
    for (int ms = 0; ms < 4; ++ms) {
        int m = ms * 16 + li;
        Arow[ms] = z ? (h0 + (size_t)m * H) : (emb + (size_t)seq[m] * H);
    }

    f32x4 acc[4][2];
#pragma unroll
    for (int ms = 0; ms < 4; ++ms)
#pragma unroll
        for (int nt = 0; nt < 2; ++nt) acc[ms][nt] = (f32x4){0.f, 0.f, 0.f, 0.f};

#define STG(BUF, KK)                                                            \
    {                                                                           \
        _Pragma("unroll")                                                       \
        for (int j = 0; j < 8; ++j) {                                           \
            int cidx = (w * 8 + j) * 64 + lane;                                 \
            int row = cidx >> 4, cs = cidx & 15;                                \
            int cg = cs ^ (row & 15);                                           \
            const float* gp = Bm + (size_t)(n0 + row) * H + (KK) + cg * 4;      \
            gl_lds16(gp, &Bs[BUF][(w * 8 + j) * 256]);                          \
        }                                                                       \
    }

#define CONSUME(BUF, KK)                                                        \
    {                                                                           \
        _Pragma("unroll")                                                       \
        for (int ks = 0; ks < 2; ++ks) {                                        \
            bf16x8 af[4];                                                       \
            _Pragma("unroll")                                                   \
            for (int ms = 0; ms < 4; ++ms) {                                    \
                float4 a0 = *(const float4*)&Arow[ms][(KK) + ks * 32 + qu * 8]; \
                float4 a1 = *(const float4*)&Arow[ms][(KK) + ks * 32 + qu * 8 + 4]; \
                af[ms][0] = (short)f2bf_rn(a0.x); af[ms][1] = (short)f2bf_rn(a0.y); \
                af[ms][2] = (short)f2bf_rn(a0.z); af[ms][3] = (short)f2bf_rn(a0.w); \
                af[ms][4] = (short)f2bf_rn(a1.x); af[ms][5] = (short)f2bf_rn(a1.y); \
                af[ms][6] = (short)f2bf_rn(a1.z); af[ms][7] = (short)f2bf_rn(a1.w); \
            }                                                                   \
            _Pragma("unroll")                                                   \
            for (int nt = 0; nt < 2; ++nt) {                                    \
                int row = w * 32 + nt * 16 + li;                                \
                int cc0 = ks * 8 + qu * 2;                                      \
                float4 x0 = *(const float4*)&Bs[BUF][row * 64 + ((cc0)     ^ (row & 15)) * 4]; \
                float4 x1 = *(const float4*)&Bs[BUF][row * 64 + ((cc0 + 1) ^ (row & 15)) * 4]; \
                bf16x8 bfr;                                                     \
                bfr[0] = (short)f2bf_rn(x0.x); bfr[1] = (short)f2bf_rn(x0.y);   \
                bfr[2] = (short)f2bf_rn(x0.z); bfr[3] = (short)f2bf_rn(x0.w);   \
                bfr[4] = (short)f2bf_rn(x1.x); bfr[5] = (short)f2bf_rn(x1.y);   \
                bfr[6] = (short)f2bf_rn(x1.z); bfr[7] = (short)f2bf_rn(x1.w);   \
                _Pragma("unroll")                                               \
                for (int ms = 0; ms < 4; ++ms)                                  \
                    acc[ms][nt] = __builtin_amdgcn_mfma_f32_16x16x32_bf16(      \
                        af[ms], bfr, acc[ms][nt], 0, 0, 0);                     \
            }                                                                   \
        }                                                                       \
    }

    STG(0, k0)
    STG(1, k0 + 64)
    for (int kt = 0; kt < 3; ++kt) {
        const int buf = kt & 1;
        wait_vm8();
        CONSUME(buf, k0 + kt * 64)
        if (kt + 2 < 4) { lds_war_guard(); STG(buf, k0 + (kt + 2) * 64) }
    }
    wait_vm0();
    CONSUME(1, k0 + 3 * 64)
#undef STG
#undef CONSUME

#pragma unroll
    for (int nt = 0; nt < 2; ++nt) {
        int col = n0 + w * 32 + nt * 16 + li;
#pragma unroll
        for (int ms = 0; ms < 4; ++ms)
#pragma unroll
            for (int j = 0; j < 4; ++j)
                C[(size_t)(ms * 16 + qu * 4 + j) * N + col] = acc[ms][nt][j];
    }
}

// ---------------------------------------------------------------------------
// GRU combine (round-9 verbatim).
__global__ void k_gru(const float* __restrict__ Pgi, const float* __restrict__ Pgh,
                      const float* __restrict__ bih, const float* __restrict__ bhh,
                      const float* __restrict__ h0, unsigned short* __restrict__ cat_bf,
                      float* __restrict__ hid) {
    int i = blockIdx.x * 256 + threadIdx.x;   // 65536
    int b = i >> 10, h = i & 1023;
    float gr = bih[h], gz = bih[H + h], gn = bih[2 * H + h];
    float hr = bhh[h], hz = bhh[H + h], hn = bhh[2 * H + h];
#pragma unroll
    for (int kt = 0; kt < 4; ++kt) {
        const float* pi = Pgi + (size_t)kt * B * 3 * H + (size_t)b * 3 * H;
        const float* ph = Pgh + (size_t)kt * B * 3 * H + (size_t)b * 3 * H;
        gr += pi[h]; gz += pi[H + h]; gn += pi[2 * H + h];
        hr += ph[h]; hz += ph[H + h]; hn += ph[2 * H + h];
    }
    float r = sigmoidf_(gr + hr);
    float z = sigmoidf_(gz + hz);
    float n = tanhf(gn + r * hn);
    float hv = (1.0f - z) * n + z * h0[i];
    cat_bf[(size_t)b * 2048 + h] = f2bf_rn(hv);
    hid[i] = hv;
}

// ---------------------------------------------------------------------------
// u-GEMM (round-9 verbatim): Pu[kc][m][n] = sum_k h[m,k]*Wa[k,n]. 128 blocks.
__global__ __launch_bounds__(256) void k_mfma_wa(const unsigned short* __restrict__ cat_bf,
                                                 const float* __restrict__ Wa,
                                                 float* __restrict__ Pu) {
    const int t = threadIdx.x;
    const int w = t >> 6, lane = t & 63;
    const int li = lane & 15, qu = lane >> 4;
    const int n0 = blockIdx.x * 64;
    const int k0 = blockIdx.y * 128;

    f32x4 acc[4];
#pragma unroll
    for (int ms = 0; ms < 4; ++ms) acc[ms] = (f32x4){0.f, 0.f, 0.f, 0.f};

    const int col = n0 + w * 16 + li;

    for (int kt = 0; kt < 2; ++kt) {
        const int kk = k0 + kt * 64;
#pragma unroll
        for (int ks = 0; ks < 2; ++ks) {
            bf16x8 af[4];
#pragma unroll
            for (int ms = 0; ms < 4; ++ms)
                af[ms] = *(const bf16x8*)&cat_bf[(size_t)(ms * 16 + li) * 2048 + kk + ks * 32 + qu * 8];
            const int kb = kk + ks * 32 + qu * 8;
            bf16x8 bfr;
#pragma unroll
            for (int e = 0; e < 8; ++e)
                bfr[e] = (short)f2bf_rn(Wa[(size_t)(kb + e) * H + col]);
#pragma unroll
            for (int ms = 0; ms < 4; ++ms)
                acc[ms] = __builtin_amdgcn_mfma_f32_16x16x32_bf16(
                    af[ms], bfr, acc[ms], 0, 0, 0);
        }
    }
    float* C = Pu + (size_t)blockIdx.y * 64 * H;
#pragma unroll
    for (int ms = 0; ms < 4; ++ms)
#pragma unroll
        for (int j = 0; j < 4; ++j)
            C[(size_t)(ms * 16 + qu * 4 + j) * H + col] = acc[ms][j];
}

// ---------------------------------------------------------------------------
// Flash attention + fused last-block combine. Block = (b, 32-row chunk),
// 16 chunks/b. After writing its partial record, the LAST block per b
// (atomic counter) re-reads the 16 records and writes context -> cat_bf.
__global__ __launch_bounds__(256) void k_flash_fc(const float* __restrict__ Pu,
                                                  const float* __restrict__ enc,
                                                  float* __restrict__ Pm,
                                                  float* __restrict__ Pl,
                                                  float* __restrict__ Pc,
                                                  unsigned short* __restrict__ cat_bf,
                                                  int* __restrict__ flags) {
    const int b = blockIdx.x >> 4, ch = blockIdx.x & 15;
    const int w = threadIdx.x >> 6, lane = threadIdx.x & 63;

    float4 uu[4];
#pragma unroll
    for (int it = 0; it < 4; ++it) {
        int col = (it * 64 + lane) * 4;
        float4 s = *(const float4*)&Pu[(size_t)b * H + col];
#pragma unroll
        for (int kt = 1; kt < 8; ++kt) {
            float4 p = *(const float4*)&Pu[(size_t)kt * B * H + (size_t)b * H + col];
            s.x += p.x; s.y += p.y; s.z += p.z; s.w += p.w;
        }
        uu[it] = s;
    }

    float m = -3.4e38f, l = 0.f;
    float4 c[4] = {{0,0,0,0},{0,0,0,0},{0,0,0,0},{0,0,0,0}};
    const float* ebase = enc + ((size_t)b * T + ch * 32 + w * 8) * H;

#pragma unroll 2
    for (int tt = 0; tt < 8; ++tt) {
        float4 e[4];
#pragma unroll
        for (int it = 0; it < 4; ++it)
            e[it] = *(const float4*)&ebase[(size_t)tt * H + (it * 64 + lane) * 4];
        float s = 0.f;
#pragma unroll
        for (int it = 0; it < 4; ++it)
            s += uu[it].x * e[it].x + uu[it].y * e[it].y +
                 uu[it].z * e[it].z + uu[it].w * e[it].w;
#pragma unroll
        for (int o = 32; o; o >>= 1) s += __shfl_xor(s, o, 64);
        float mn = fmaxf(m, s);
        float scale = __expf(m - mn);
        float p = __expf(s - mn);
        l = l * scale + p;
#pragma unroll
        for (int it = 0; it < 4; ++it) {
            c[it].x = fmaf(p, e[it].x, c[it].x * scale);
            c[it].y = fmaf(p, e[it].y, c[it].y * scale);
            c[it].z = fmaf(p, e[it].z, c[it].z * scale);
            c[it].w = fmaf(p, e[it].w, c[it].w * scale);
        }
        m = mn;
    }

    __shared__ float Lm[4], Ll[4];
    __shared__ __align__(16) float Lc[4][H];
    __shared__ int isLast;
#pragma unroll
    for (int it = 0; it < 4; ++it)
        *(float4*)&Lc[w][(it * 64 + lane) * 4] = c[it];
    if (lane == 0) { Lm[w] = m; Ll[w] = l; }
    __syncthreads();

    float M = fmaxf(fmaxf(Lm[0], Lm[1]), fmaxf(Lm[2], Lm[3]));
    float e0 = __expf(Lm[0] - M), e1 = __expf(Lm[1] - M),
          e2 = __expf(Lm[2] - M), e3 = __expf(Lm[3] - M);
    float L = Ll[0] * e0 + Ll[1] * e1 + Ll[2] * e2 + Ll[3] * e3;
    int col = threadIdx.x * 4;
    float4 c0 = *(const float4*)&Lc[0][col];
    float4 c1 = *(const float4*)&Lc[1][col];
    float4 c2 = *(const float4*)&Lc[2][col];
    float4 c3 = *(const float4*)&Lc[3][col];
    float4 cc;
    cc.x = c0.x * e0 + c1.x * e1 + c2.x * e2 + c3.x * e3;
    cc.y = c0.y * e0 + c1.y * e1 + c2.y * e2 + c3.y * e3;
    cc.z = c0.z * e0 + c1.z * e1 + c2.z * e2 + c3.z * e3;
    cc.w = c0.w * e0 + c1.w * e1 + c2.w * e2 + c3.w * e3;
    const int rec = blockIdx.x;   // b*16 + ch
    if (threadIdx.x == 0) { Pm[rec] = M; Pl[rec] = L; }
    *(float4*)&Pc[(size_t)rec * H + col] = cc;

    // ---- last-block-per-b combine (deadlock-free, no co-residency needed) ----
    __threadfence();                       // make Pm/Pl/Pc visible device-wide
    if (threadIdx.x == 0)
        isLast = (atomicAdd(&flags[b], 1) == 15);
    __syncthreads();
    if (!isLast) return;
    __threadfence();                       // acquire: others' records visible

    float Mg = -3.4e38f;
#pragma unroll
    for (int i = 0; i < 16; ++i) Mg = fmaxf(Mg, Pm[b * 16 + i]);
    float Lg = 0.f;
    float4 ccg = {0, 0, 0, 0};
#pragma unroll 4
    for (int i = 0; i < 16; ++i) {
        float wgt = __expf(Pm[b * 16 + i] - Mg);
        Lg += Pl[b * 16 + i] * wgt;
        float4 p = *(const float4*)&Pc[(size_t)(b * 16 + i) * H + col];
        ccg.x += wgt * p.x; ccg.y += wgt * p.y;
        ccg.z += wgt * p.z; ccg.w += wgt * p.w;
    }
    float inv = 1.0f / Lg;
    ushort4 o;
    o.x = f2bf_rn(ccg.x * inv); o.y = f2bf_rn(ccg.y * inv);
    o.z = f2bf_rn(ccg.z * inv); o.w = f2bf_rn(ccg.w * inv);
    *(ushort4*)&cat_bf[(size_t)b * 2048 + 1024 + col] = o;
}

// ---------------------------------------------------------------------------
// Wc GEMM + fused last-block tanh/bf16. C[m,n] = sum_k cat[m,k]*Wc[n,k].
// BN=128 (8 n-blocks), KC=128 (16 K-chunks). Last block per n-slice sums the
// 16 partials, adds b_c, tanh, writes co_bf slice.
__global__ __launch_bounds__(256) void k_wc_co(const unsigned short* __restrict__ A,
                                               const float* __restrict__ Wc,
                                               const float* __restrict__ bc,
                                               float* __restrict__ Pcg,
                                               unsigned short* __restrict__ co_bf,
                                               int* __restrict__ flags) {
    __shared__ __align__(16) float Bs[2][128 * 64];
    float* C = Pcg + (size_t)blockIdx.y * 64 * H;
    const int t = threadIdx.x;
    const int w = t >> 6, lane = t & 63;
    const int li = lane & 15, qu = lane >> 4;
    const int n0 = blockIdx.x * 128;
    const int k0 = blockIdx.y * 128;

    f32x4 acc[4][2];
#pragma unroll
    for (int ms = 0; ms < 4; ++ms)
#pragma unroll
        for (int nt = 0; nt < 2; ++nt) acc[ms][nt] = (f32x4){0.f, 0.f, 0.f, 0.f};

#define STG(BUF, KK)                                                            \
    {                                                                           \
        _Pragma("unroll")                                                       \
        for (int j = 0; j < 8; ++j) {                                           \
            int cidx = (w * 8 + j) * 64 + lane;                                 \
            int row = cidx >> 4, cs = cidx & 15;                                \
            int cg = cs ^ (row & 15);                                           \
            const float* gp = Wc + (size_t)(n0 + row) * (2 * H) + (KK) + cg * 4; \
            gl_lds16(gp, &Bs[BUF][(w * 8 + j) * 256]);                          \
        }                                                                       \
    }

#define CONSUME(BUF, KK)                                                        \
    {                                                                           \
        _Pragma("unroll")                                                       \
        for (int ks = 0; ks < 2; ++ks) {                                        \
            bf16x8 af[4];                                                       \
            _Pragma("unroll")                                                   \
            for (int ms = 0; ms < 4; ++ms)                                      \
                af[ms] = *(const bf16x8*)&A[(size_t)(ms * 16 + li) * 2048 + (KK) + ks * 32 + qu * 8]; \
            _Pragma("unroll")                                                   \
            for (int nt = 0; nt < 2; ++nt) {                                    \
                int row = w * 32 + nt * 16 + li;                                \
                int cc0 = ks * 8 + qu * 2;                                      \
                float4 x0 = *(const float4*)&Bs[BUF][row * 64 + ((cc0)     ^ (row & 15)) * 4]; \
                float4 x1 = *(const float4*)&Bs[BUF][row * 64 + ((cc0 + 1) ^ (row & 15)) * 4]; \
                bf16x8 bfr;                                                     \
                bfr[0] = (short)f2bf_rn(x0.x); bfr[1] = (short)f2bf_rn(x0.y);   \
                bfr[2] = (short)f2bf_rn(x0.z); bfr[3] = (short)f2bf_rn(x0.w);   \
                bfr[4] = (short)f2bf_rn(x1.x); bfr[5] = (short)f2bf_rn(x1.y);   \
                bfr[6] = (short)f2bf_rn(x1.z); bfr[7] = (short)f2bf_rn(x1.w);   \
                _Pragma("unroll")                                               \
                for (int ms = 0; ms < 4; ++ms)                                  \
                    acc[ms][nt] = __builtin_amdgcn_mfma_f32_16x16x32_bf16(      \
                        af[ms], bfr, acc[ms][nt], 0, 0, 0);                     \
            }                                                                   \
        }                                                                       \
    }

    STG(0, k0)
    STG(1, k0 + 64)
    wait_vm8();
    CONSUME(0, k0)
    wait_vm0();
    CONSUME(1, k0 + 64)
#undef STG
#undef CONSUME

#pragma unroll
    for (int nt = 0; nt < 2; ++nt) {
        int col = n0 + w * 32 + nt * 16 + li;
#pragma unroll
        for (int ms = 0; ms < 4; ++ms)
#pragma unroll
            for (int j = 0; j < 4; ++j)
                C[(size_t)(ms * 16 + qu * 4 + j) * H + col] = acc[ms][nt][j];
    }

    // ---- last-block-per-n-slice: co = tanh(sum 16 partials + b_c) -> bf16 ----
    __shared__ int isLast;
    __threadfence();
    if (t == 0)
        isLast = (atomicAdd(&flags[blockIdx.x], 1) == 15);
    __syncthreads();
    if (!isLast) return;
    __threadfence();

    // slice: all 64 rows x cols [n0, n0+128): 8192 elems, 32 per thread
#pragma unroll
    for (int e = 0; e < 32; ++e) {
        int elem = e * 256 + t;
        int m_ = elem >> 7, c_ = elem & 127;
        int n = n0 + c_;
        float s = bc[n];
#pragma unroll 4
        for (int kt = 0; kt < 16; ++kt)
            s += Pcg[(size_t)kt * B * H + (size_t)m_ * H + n];
        co_bf[(size_t)m_ * H + n] = f2bf_rn(tanhf(s));
    }
}

// ---------------------------------------------------------------------------
// Output GEMM (round-9 verbatim): out[b,v] = sum_h co[b,h]*Wo[v,h]+bo[v].
__global__ __launch_bounds__(256) void k_out_mfma(const unsigned short* __restrict__ co_bf,
                                                  const float* __restrict__ Wo,
                                                  const float* __restrict__ bo,
                                                  float* __restrict__ out) {
    __shared__ __align__(16) float Bs[2][128 * 64];
    const int t = threadIdx.x;
    const int w = t >> 6, lane = t & 63;
    const int li = lane & 15, qu = lane >> 4;
    const int v0 = blockIdx.x * 128;

    f32x4 acc[4][2];
#pragma unroll
    for (int ms = 0; ms < 4; ++ms)
#pragma unroll
        for (int nt = 0; nt < 2; ++nt) acc[ms][nt] = (f32x4){0.f, 0.f, 0.f, 0.f};

#define STAGE(BUF, KK)                                                          \
    {                                                                           \
        _Pragma("unroll")                                                       \
        for (int j = 0; j < 8; ++j) {                                           \
            int cidx = (w * 8 + j) * 64 + lane;                                 \
            int row = cidx >> 4, cs = cidx & 15;                                \
            int cg = cs ^ (row & 15);                                           \
            int vr = v0 + row; if (vr >= V) vr = V - 1;                         \
            const float* gp = Wo + (size_t)vr * H + (KK) + cg * 4;              \
            gl_lds16(gp, &Bs[BUF][(w * 8 + j) * 256]);                          \
        }                                                                       \
    }

#define CONSUME(BUF, KK)                                                        \
    {                                                                           \
        _Pragma("unroll")                                                       \
        for (int ks = 0; ks < 2; ++ks) {                                        \
            bf16x8 af[4];                                                       \
            _Pragma("unroll")                                                   \
            for (int ms = 0; ms < 4; ++ms)                                      \
                af[ms] = *(const bf16x8*)&co_bf[(size_t)(ms * 16 + li) * H + (KK) + ks * 32 + qu * 8]; \
            _Pragma("unroll")                                                   \
            for (int nt = 0; nt < 2; ++nt) {                                    \
                int row = w * 32 + nt * 16 + li;                                \
                int cc0 = ks * 8 + qu * 2;                                      \
                float4 x0 = *(const float4*)&Bs[BUF][row * 64 + ((cc0)     ^ (row & 15)) * 4]; \
                float4 x1 = *(const float4*)&Bs[BUF][row * 64 + ((cc0 + 1) ^ (row & 15)) * 4]; \
                bf16x8 bfr;                                                     \
                bfr[0] = (short)f2bf_rn(x0.x); bfr[1] = (short)f2bf_rn(x0.y);   \
                bfr[2] = (short)f2bf_rn(x0.z); bfr[3] = (short)f2bf_rn(x0.w);   \
                bfr[4] = (short)f2bf_rn(x1.x); bfr[5] = (short)f2bf_rn(x1.y);   \
                bfr[6] = (short)f2bf_rn(x1.z); bfr[7] = (short)f2bf_rn(x1.w);   \
                _Pragma("unroll")                                               \
                for (int ms = 0; ms < 4; ++ms)                                  \
                    acc[ms][nt] = __builtin_amdgcn_mfma_f32_16x16x32_bf16(      \
                        af[ms], bfr, acc[ms][nt], 0, 0, 0);                     \
            }                                                                   \
        }                                                                       \
    }

    STAGE(0, 0)
    STAGE(1, 64)
    for (int kt = 0; kt < 15; ++kt) {
        const int buf = kt & 1;
        wait_vm8();
        CONSUME(buf, kt * 64)
        if (kt + 2 < 16) { lds_war_guard(); STAGE(buf, (kt + 2) * 64) }
    }
    wait_vm0();
    CONSUME(1, 15 * 64)
#undef STAGE
#undef CONSUME

#pragma unroll
    for (int nt = 0; nt < 2; ++nt) {
        int v = v0 + w * 32 + nt * 16 + li;
        if (v < V) {
            float bov = bo[v];
#pragma unroll
            for (int ms = 0; ms < 4; ++ms)
#pragma unroll
                for (int j = 0; j < 4; ++j)
                    out[(size_t)(ms * 16 + qu * 4 + j) * V + v] = acc[ms][nt][j] + bov;
        }
    }
}

// ---------------------------------------------------------------------------
extern "C" void kernel_launch(void* const* d_in, const int* in_sizes, int n_in,
                              void* d_out, int out_size, void* d_ws, size_t ws_size,
                              hipStream_t stream) {
    (void)in_sizes; (void)n_in; (void)out_size; (void)ws_size;
    const int*   seq = (const int*)d_in[0];
    const float* h0  = (const float*)d_in[1];
    const float* enc = (const float*)d_in[2];
    const float* emb = (const float*)d_in[3];
    const float* Wih = (const float*)d_in[4];
    const float* Whh = (const float*)d_in[5];
    const float* bih = (const float*)d_in[6];
    const float* bhh = (const float*)d_in[7];
    const float* Wa  = (const float*)d_in[8];
    // d_in[9] = b_a: softmax over t is invariant to the per-b constant h·b_a -> unused
    const float* Wc  = (const float*)d_in[10];
    const float* bc  = (const float*)d_in[11];
    const float* Wo  = (const float*)d_in[12];
    const float* bo  = (const float*)d_in[13];

    float* out = (float*)d_out;
    float* hid = out + (size_t)B * V;

    float* ws   = (float*)d_ws;
    float* Pgi  = ws;                     // 786432
    float* Pgh  = Pgi + 786432;           // 786432
    float* Pu   = Pgh + 786432;           // 524288 (8 partials)
    float* Pm   = Pu + 524288;            // 1024
    float* Pl   = Pm + 1024;              // 1024
    float* Pc   = Pl + 1024;              // 1048576 (1024 recs x 1024)
    float* Pcg  = Pc + 1048576;           // 1048576 (16 partials)
    unsigned short* cat_bf = (unsigned short*)(Pcg + 1048576); // 131072 us
    unsigned short* co_bf  = cat_bf + 131072;                  // 65536 us
    int* flags  = (int*)(co_bf + 65536);  // 64 (flash) + 8 (wc) ints

    hipMemsetAsync(flags, 0, 72 * sizeof(int), stream);

    k_gates<<<dim3(24, 4, 2), 256, 0, stream>>>(seq, emb, h0, Wih, Whh, Pgi, Pgh);
    k_gru<<<256, 256, 0, stream>>>(Pgi, Pgh, bih, bhh, h0, cat_bf, hid);
    k_mfma_wa<<<dim3(16, 8), 256, 0, stream>>>(cat_bf, Wa, Pu);
    k_flash_fc<<<1024, 256, 0, stream>>>(Pu, enc, Pm, Pl, Pc, cat_bf, flags);
    k_wc_co<<<dim3(8, 16), 256, 0, stream>>>(cat_bf, Wc, bc, Pcg, co_bf, flags + 64);
    k_out_mfma<<<(V + 127) / 128, 256, 0, stream>>>(co_bf, Wo, bo, out);
}

// Round 12
// 134.302 us; speedup vs baseline: 3.3344x; 3.3344x over previous
//
#include <hip/hip_runtime.h>
#include <hip/hip_bf16.h>
#include <cstdint>
#include <cstddef>

#define H 1024
#define V 50257
#define B 64
#define T 512

typedef __attribute__((ext_vector_type(8))) short bf16x8;
typedef __attribute__((ext_vector_type(4))) float f32x4;

__device__ __forceinline__ float sigmoidf_(float x) { return 1.0f / (1.0f + expf(-x)); }

__device__ __forceinline__ unsigned short f2bf_rn(float x) {
    __hip_bfloat16 h = __float2bfloat16(x);
    return __builtin_bit_cast(unsigned short, h);
}

__device__ __forceinline__ void gl_lds16(const float* g, float* l) {
    __builtin_amdgcn_global_load_lds(
        (const __attribute__((address_space(1))) unsigned*)g,
        (__attribute__((address_space(3))) unsigned*)l, 16, 0, 0);
}

__device__ __forceinline__ void wait_vm8() {
    asm volatile("s_waitcnt vmcnt(8)" ::: "memory");
    __builtin_amdgcn_sched_barrier(0);
}
__device__ __forceinline__ void wait_vm0() {
    asm volatile("s_waitcnt vmcnt(0)" ::: "memory");
    __builtin_amdgcn_sched_barrier(0);
}
__device__ __forceinline__ void lds_war_guard() {
    asm volatile("s_waitcnt lgkmcnt(0)" ::: "memory");
    __builtin_amdgcn_sched_barrier(0);
}

// ---------------------------------------------------------------------------
// Gate GEMMs: z=0: Pgi = bf16(emb[seq]) @ Wih^T ; z=1: Pgh = bf16(h0) @ Whh^T.
// M=64, BN=128, split-K (KC=256, grid.y=4). Barrier-free + 2-ahead vmcnt.
__global__ __launch_bounds__(256) void k_gates(const int* __restrict__ seq,
                                               const float* __restrict__ emb,
                                               const float* __restrict__ h0,
                                               const float* __restrict__ Wih,
                                               const float* __restrict__ Whh,
                                               float* __restrict__ Pgi,
                                               float* __restrict__ Pgh) {
    __shared__ __align__(16) float Bs[2][128 * 64];
    const int z = blockIdx.z;
    const float* Bm = z ? Whh : Wih;
    float* C = (z ? Pgh : Pgi) + (size_t)blockIdx.y * 64 * (3 * H);
    const int t = threadIdx.x;
    const int w = t >> 6, lane = t & 63;
    const int li = lane & 15, qu = lane >> 4;
    const int n0 = blockIdx.x * 128;
    const int k0 = blockIdx.y * 256;
    const int N = 3 * H;

    const float* Arow[4];
#pragma unroll
    for (int ms = 0; ms < 4; ++ms) {
        int m = ms * 16 + li;
        Arow[ms] = z ? (h0 + (size_t)m * H) : (emb + (size_t)seq[m] * H);
    }

    f32x4 acc[4][2];
#pragma unroll
    for (int ms = 0; ms < 4; ++ms)
#pragma unroll
        for (int nt = 0; nt < 2; ++nt) acc[ms][nt] = (f32x4){0.f, 0.f, 0.f, 0.f};

#define STG(BUF, KK)                                                            \
    {                                                                           \
        _Pragma("unroll")                                                       \
        for (int j = 0; j < 8; ++j) {                                           \
            int cidx = (w * 8 + j) * 64 + lane;                                 \
            int row = cidx >> 4, cs = cidx & 15;                                \
            int cg = cs ^ (row & 15);                                           \
            const float* gp = Bm + (size_t)(n0 + row) * H + (KK) + cg * 4;      \
            gl_lds16(gp, &Bs[BUF][(w * 8 + j) * 256]);                          \
        }                                                                       \
    }

#define CONSUME(BUF, KK)                                                        \
    {                                                                           \
        _Pragma("unroll")                                                       \
        for (int ks = 0; ks < 2; ++ks) {                                        \
            bf16x8 af[4];                                                       \
            _Pragma("unroll")                                                   \
            for (int ms = 0; ms < 4; ++ms) {                                    \
                float4 a0 = *(const float4*)&Arow[ms][(KK) + ks * 32 + qu * 8]; \
                float4 a1 = *(const float4*)&Arow[ms][(KK) + ks * 32 + qu * 8 + 4]; \
                af[ms][0] = (short)f2bf_rn(a0.x); af[ms][1] = (short)f2bf_rn(a0.y); \
                af[ms][2] = (short)f2bf_rn(a0.z); af[ms][3] = (short)f2bf_rn(a0.w); \
                af[ms][4] = (short)f2bf_rn(a1.x); af[ms][5] = (short)f2bf_rn(a1.y); \
                af[ms][6] = (short)f2bf_rn(a1.z); af[ms][7] = (short)f2bf_rn(a1.w); \
            }                                                                   \
            _Pragma("unroll")                                                   \
            for (int nt = 0; nt < 2; ++nt) {                                    \
                int row = w * 32 + nt * 16 + li;                                \
                int cc0 = ks * 8 + qu * 2;                                      \
                float4 x0 = *(const float4*)&Bs[BUF][row * 64 + ((cc0)     ^ (row & 15)) * 4]; \
                float4 x1 = *(const float4*)&Bs[BUF][row * 64 + ((cc0 + 1) ^ (row & 15)) * 4]; \
                bf16x8 bfr;                                                     \
                bfr[0] = (short)f2bf_rn(x0.x); bfr[1] = (short)f2bf_rn(x0.y);   \
                bfr[2] = (short)f2bf_rn(x0.z); bfr[3] = (short)f2bf_rn(x0.w);   \
                bfr[4] = (short)f2bf_rn(x1.x); bfr[5] = (short)f2bf_rn(x1.y);   \
                bfr[6] = (short)f2bf_rn(x1.z); bfr[7] = (short)f2bf_rn(x1.w);   \
                _Pragma("unroll")                                               \
                for (int ms = 0; ms < 4; ++ms)                                  \
                    acc[ms][nt] = __builtin_amdgcn_mfma_f32_16x16x32_bf16(      \
                        af[ms], bfr, acc[ms][nt], 0, 0, 0);                     \
            }                                                                   \
        }                                                                       \
    }

    STG(0, k0)
    STG(1, k0 + 64)
    for (int kt = 0; kt < 3; ++kt) {
        const int buf = kt & 1;
        wait_vm8();
        CONSUME(buf, k0 + kt * 64)
        if (kt + 2 < 4) { lds_war_guard(); STG(buf, k0 + (kt + 2) * 64) }
    }
    wait_vm0();
    CONSUME(1, k0 + 3 * 64)
#undef STG
#undef CONSUME

#pragma unroll
    for (int nt = 0; nt < 2; ++nt) {
        int col = n0 + w * 32 + nt * 16 + li;
#pragma unroll
        for (int ms = 0; ms < 4; ++ms)
#pragma unroll
            for (int j = 0; j < 4; ++j)
                C[(size_t)(ms * 16 + qu * 4 + j) * N + col] = acc[ms][nt][j];
    }
}

// ---------------------------------------------------------------------------
// Wc GEMM via bf16 MFMA, B row-major-in-K. C[m,n] = sum_k A[m,k]*Bm[n,k].
// Barrier-free + 2-ahead counted vmcnt.  nsteps = KC/64 (>=2).
__global__ __launch_bounds__(256) void k_mfma_bt(const unsigned short* __restrict__ A,
                                                 int lda,
                                                 const float* __restrict__ Bm, int ldb,
                                                 float* __restrict__ Cp, int N, int KC) {
    __shared__ __align__(16) float Bs[2][128 * 64];
    float* C = Cp + (size_t)blockIdx.y * 64 * N;
    const int t = threadIdx.x;
    const int w = t >> 6, lane = t & 63;
    const int li = lane & 15, qu = lane >> 4;
    const int n0 = blockIdx.x * 128;
    const int k0 = blockIdx.y * KC;
    const int nsteps = KC >> 6;

    f32x4 acc[4][2];
#pragma unroll
    for (int ms = 0; ms < 4; ++ms)
#pragma unroll
        for (int nt = 0; nt < 2; ++nt) acc[ms][nt] = (f32x4){0.f, 0.f, 0.f, 0.f};

#define STG(BUF, KK)                                                            \
    {                                                                           \
        _Pragma("unroll")                                                       \
        for (int j = 0; j < 8; ++j) {                                           \
            int cidx = (w * 8 + j) * 64 + lane;                                 \
            int row = cidx >> 4, cs = cidx & 15;                                \
            int cg = cs ^ (row & 15);                                           \
            const float* gp = Bm + (size_t)(n0 + row) * ldb + (KK) + cg * 4;    \
            gl_lds16(gp, &Bs[BUF][(w * 8 + j) * 256]);                          \
        }                                                                       \
    }

#define CONSUME(BUF, KK)                                                        \
    {                                                                           \
        _Pragma("unroll")                                                       \
        for (int ks = 0; ks < 2; ++ks) {                                        \
            bf16x8 af[4];                                                       \
            _Pragma("unroll")                                                   \
            for (int ms = 0; ms < 4; ++ms)                                      \
                af[ms] = *(const bf16x8*)&A[(size_t)(ms * 16 + li) * lda + (KK) + ks * 32 + qu * 8]; \
            _Pragma("unroll")                                                   \
            for (int nt = 0; nt < 2; ++nt) {                                    \
                int row = w * 32 + nt * 16 + li;                                \
                int cc0 = ks * 8 + qu * 2;                                      \
                float4 x0 = *(const float4*)&Bs[BUF][row * 64 + ((cc0)     ^ (row & 15)) * 4]; \
                float4 x1 = *(const float4*)&Bs[BUF][row * 64 + ((cc0 + 1) ^ (row & 15)) * 4]; \
                bf16x8 bfr;                                                     \
                bfr[0] = (short)f2bf_rn(x0.x); bfr[1] = (short)f2bf_rn(x0.y);   \
                bfr[2] = (short)f2bf_rn(x0.z); bfr[3] = (short)f2bf_rn(x0.w);   \
                bfr[4] = (short)f2bf_rn(x1.x); bfr[5] = (short)f2bf_rn(x1.y);   \
                bfr[6] = (short)f2bf_rn(x1.z); bfr[7] = (short)f2bf_rn(x1.w);   \
                _Pragma("unroll")                                               \
                for (int ms = 0; ms < 4; ++ms)                                  \
                    acc[ms][nt] = __builtin_amdgcn_mfma_f32_16x16x32_bf16(      \
                        af[ms], bfr, acc[ms][nt], 0, 0, 0);                     \
            }                                                                   \
        }                                                                       \
    }

    STG(0, k0)
    STG(1, k0 + 64)
    for (int kt = 0; kt < nsteps - 1; ++kt) {
        const int buf = kt & 1;
        wait_vm8();
        CONSUME(buf, k0 + kt * 64)
        if (kt + 2 < nsteps) { lds_war_guard(); STG(buf, k0 + (kt + 2) * 64) }
    }
    wait_vm0();
    CONSUME((nsteps - 1) & 1, k0 + (nsteps - 1) * 64)
#undef STG
#undef CONSUME

#pragma unroll
    for (int nt = 0; nt < 2; ++nt) {
        int col = n0 + w * 32 + nt * 16 + li;
#pragma unroll
        for (int ms = 0; ms < 4; ++ms)
#pragma unroll
            for (int j = 0; j < 4; ++j)
                C[(size_t)(ms * 16 + qu * 4 + j) * N + col] = acc[ms][nt][j];
    }
}

// ---------------------------------------------------------------------------
// u-GEMM (B column-major-in-K): Pu[m,n] += sum_k h[m,k] * Wa[k,n].
// BN=64, KC=128 -> dim3(16,8) = 128 blocks.
__global__ __launch_bounds__(256) void k_mfma_wa(const unsigned short* __restrict__ cat_bf,
                                                 const float* __restrict__ Wa,
                                                 float* __restrict__ Pu) {
    const int t = threadIdx.x;
    const int w = t >> 6, lane = t & 63;
    const int li = lane & 15, qu = lane >> 4;
    const int n0 = blockIdx.x * 64;
    const int k0 = blockIdx.y * 128;

    f32x4 acc[4];
#pragma unroll
    for (int ms = 0; ms < 4; ++ms) acc[ms] = (f32x4){0.f, 0.f, 0.f, 0.f};

    const int col = n0 + w * 16 + li;

    for (int kt = 0; kt < 2; ++kt) {
        const int kk = k0 + kt * 64;
#pragma unroll
        for (int ks = 0; ks < 2; ++ks) {
            bf16x8 af[4];
#pragma unroll
            for (int ms = 0; ms < 4; ++ms)
                af[ms] = *(const bf16x8*)&cat_bf[(size_t)(ms * 16 + li) * 2048 + kk + ks * 32 + qu * 8];
            const int kb = kk + ks * 32 + qu * 8;
            bf16x8 bfr;
#pragma unroll
            for (int e = 0; e < 8; ++e)
                bfr[e] = (short)f2bf_rn(Wa[(size_t)(kb + e) * H + col]);
#pragma unroll
            for (int ms = 0; ms < 4; ++ms)
                acc[ms] = __builtin_amdgcn_mfma_f32_16x16x32_bf16(
                    af[ms], bfr, acc[ms], 0, 0, 0);
        }
    }
    float* C = Pu + (size_t)blockIdx.y * 64 * H;
#pragma unroll
    for (int ms = 0; ms < 4; ++ms)
#pragma unroll
        for (int j = 0; j < 4; ++j)
            C[(size_t)(ms * 16 + qu * 4 + j) * H + col] = acc[ms][j];
}

// ---------------------------------------------------------------------------
// GRU combine: fp32 partial sums -> h. Writes hid (fp32) and cat_bf[:, :H].
__global__ void k_gru(const float* __restrict__ Pgi, const float* __restrict__ Pgh,
                      const float* __restrict__ bih, const float* __restrict__ bhh,
                      const float* __restrict__ h0, unsigned short* __restrict__ cat_bf,
                      float* __restrict__ hid) {
    int i = blockIdx.x * 256 + threadIdx.x;   // 65536
    int b = i >> 10, h = i & 1023;
    float gr = bih[h], gz = bih[H + h], gn = bih[2 * H + h];
    float hr = bhh[h], hz = bhh[H + h], hn = bhh[2 * H + h];
#pragma unroll
    for (int kt = 0; kt < 4; ++kt) {
        const float* pi = Pgi + (size_t)kt * B * 3 * H + (size_t)b * 3 * H;
        const float* ph = Pgh + (size_t)kt * B * 3 * H + (size_t)b * 3 * H;
        gr += pi[h]; gz += pi[H + h]; gn += pi[2 * H + h];
        hr += ph[h]; hz += ph[H + h]; hn += ph[2 * H + h];
    }
    float r = sigmoidf_(gr + hr);
    float z = sigmoidf_(gz + hz);
    float n = tanhf(gn + r * hn);
    float hv = (1.0f - z) * n + z * h0[i];
    cat_bf[(size_t)b * 2048 + h] = f2bf_rn(hv);
    hid[i] = hv;
}

// ---------------------------------------------------------------------------
// Flash attention: block = (b, 32-row chunk), 4 waves x 8 rows. Online softmax
// per wave, 4-wave LDS combine -> 1024 partial records. Deep unroll (4) to
// widen the enc-load window across the serial shuffle-reduce chains.
__global__ __launch_bounds__(256) void k_flash(const float* __restrict__ Pu,
                                               const float* __restrict__ enc,
                                               float* __restrict__ Pm,
                                               float* __restrict__ Pl,
                                               float* __restrict__ Pc) {
    const int b = blockIdx.x >> 4, ch = blockIdx.x & 15;
    const int w = threadIdx.x >> 6, lane = threadIdx.x & 63;

    float4 uu[4];
#pragma unroll
    for (int it = 0; it < 4; ++it) {
        int col = (it * 64 + lane) * 4;
        float4 s = *(const float4*)&Pu[(size_t)b * H + col];
#pragma unroll
        for (int kt = 1; kt < 8; ++kt) {
            float4 p = *(const float4*)&Pu[(size_t)kt * B * H + (size_t)b * H + col];
            s.x += p.x; s.y += p.y; s.z += p.z; s.w += p.w;
        }
        uu[it] = s;
    }

    float m = -3.4e38f, l = 0.f;
    float4 c[4] = {{0,0,0,0},{0,0,0,0},{0,0,0,0},{0,0,0,0}};
    const float* ebase = enc + ((size_t)b * T + ch * 32 + w * 8) * H;

#pragma unroll 4
    for (int tt = 0; tt < 8; ++tt) {
        float4 e[4];
#pragma unroll
        for (int it = 0; it < 4; ++it)
            e[it] = *(const float4*)&ebase[(size_t)tt * H + (it * 64 + lane) * 4];
        float s = 0.f;
#pragma unroll
        for (int it = 0; it < 4; ++it)
            s += uu[it].x * e[it].x + uu[it].y * e[it].y +
                 uu[it].z * e[it].z + uu[it].w * e[it].w;
#pragma unroll
        for (int o = 32; o; o >>= 1) s += __shfl_xor(s, o, 64);
        float mn = fmaxf(m, s);
        float scale = __expf(m - mn);
        float p = __expf(s - mn);
        l = l * scale + p;
#pragma unroll
        for (int it = 0; it < 4; ++it) {
            c[it].x = fmaf(p, e[it].x, c[it].x * scale);
            c[it].y = fmaf(p, e[it].y, c[it].y * scale);
            c[it].z = fmaf(p, e[it].z, c[it].z * scale);
            c[it].w = fmaf(p, e[it].w, c[it].w * scale);
        }
        m = mn;
    }

    __shared__ float Lm[4], Ll[4];
    __shared__ __align__(16) float Lc[4][H];
#pragma unroll
    for (int it = 0; it < 4; ++it)
        *(float4*)&Lc[w][(it * 64 + lane) * 4] = c[it];
    if (lane == 0) { Lm[w] = m; Ll[w] = l; }
    __syncthreads();

    float M = fmaxf(fmaxf(Lm[0], Lm[1]), fmaxf(Lm[2], Lm[3]));
    float e0 = __expf(Lm[0] - M), e1 = __expf(Lm[1] - M),
          e2 = __expf(Lm[2] - M), e3 = __expf(Lm[3] - M);
    float L = Ll[0] * e0 + Ll[1] * e1 + Ll[2] * e2 + Ll[3] * e3;
    int col = threadIdx.x * 4;
    float4 c0 = *(const float4*)&Lc[0][col];
    float4 c1 = *(const float4*)&Lc[1][col];
    float4 c2 = *(const float4*)&Lc[2][col];
    float4 c3 = *(const float4*)&Lc[3][col];
    float4 cc;
    cc.x = c0.x * e0 + c1.x * e1 + c2.x * e2 + c3.x * e3;
    cc.y = c0.y * e0 + c1.y * e1 + c2.y * e2 + c3.y * e3;
    cc.z = c0.z * e0 + c1.z * e1 + c2.z * e2 + c3.z * e3;
    cc.w = c0.w * e0 + c1.w * e1 + c2.w * e2 + c3.w * e3;
    const int rec = blockIdx.x;   // b*16 + ch
    if (threadIdx.x == 0) { Pm[rec] = M; Pl[rec] = L; }
    *(float4*)&Pc[(size_t)rec * H + col] = cc;
}

// Combine 16 chunk-partials per b -> context -> cat_bf[:, H:2H]
__global__ void k_fcomb(const float* __restrict__ Pm, const float* __restrict__ Pl,
                        const float* __restrict__ Pc, unsigned short* __restrict__ cat_bf) {
    const int b = blockIdx.x;
    const int col = threadIdx.x * 4;
    float M = -3.4e38f;
#pragma unroll
    for (int i = 0; i < 16; ++i) M = fmaxf(M, Pm[b * 16 + i]);
    float L = 0.f;
    float4 cc = {0, 0, 0, 0};
#pragma unroll 4
    for (int i = 0; i < 16; ++i) {
        float wgt = __expf(Pm[b * 16 + i] - M);
        L += Pl[b * 16 + i] * wgt;
        float4 p = *(const float4*)&Pc[(size_t)(b * 16 + i) * H + col];
        cc.x += wgt * p.x; cc.y += wgt * p.y;
        cc.z += wgt * p.z; cc.w += wgt * p.w;
    }
    float inv = 1.0f / L;
    ushort4 o;
    o.x = f2bf_rn(cc.x * inv); o.y = f2bf_rn(cc.y * inv);
    o.z = f2bf_rn(cc.z * inv); o.w = f2bf_rn(cc.w * inv);
    *(ushort4*)&cat_bf[(size_t)b * 2048 + 1024 + col] = o;
}

// co = tanh(sum partials + b_c), written as bf16  (16 K-partials)
__global__ void k_co(const float* __restrict__ Pc, const float* __restrict__ bc,
                     unsigned short* __restrict__ co_bf) {
    int i = blockIdx.x * 256 + threadIdx.x;
    int h = i & 1023;
    float s = bc[h];
#pragma unroll
    for (int kt = 0; kt < 16; ++kt) s += Pc[kt * (B * H) + i];
    co_bf[i] = f2bf_rn(tanhf(s));
}

// ---------------------------------------------------------------------------
// Output GEMM: out[b,v] = sum_h co[b,h]*Wo[v,h] + bo[v].  BN=128, BK=64.
// Barrier-free wave-private LDS rows + 2-ahead counted-vmcnt staging.
__global__ __launch_bounds__(256) void k_out_mfma(const unsigned short* __restrict__ co_bf,
                                                  const float* __restrict__ Wo,
                                                  const float* __restrict__ bo,
                                                  float* __restrict__ out) {
    __shared__ __align__(16) float Bs[2][128 * 64];
    const int t = threadIdx.x;
    const int w = t >> 6, lane = t & 63;
    const int li = lane & 15, qu = lane >> 4;
    const int v0 = blockIdx.x * 128;

    f32x4 acc[4][2];
#pragma unroll
    for (int ms = 0; ms < 4; ++ms)
#pragma unroll
        for (int nt = 0; nt < 2; ++nt) acc[ms][nt] = (f32x4){0.f, 0.f, 0.f, 0.f};

#define STAGE(BUF, KK)                                                          \
    {                                                                           \
        _Pragma("unroll")                                                       \
        for (int j = 0; j < 8; ++j) {                                           \
            int cidx = (w * 8 + j) * 64 + lane;                                 \
            int row = cidx >> 4, cs = cidx & 15;                                \
            int cg = cs ^ (row & 15);                                           \
            int vr = v0 + row; if (vr >= V) vr = V - 1;                         \
            const float* gp = Wo + (size_t)vr * H + (KK) + cg * 4;              \
            gl_lds16(gp, &Bs[BUF][(w * 8 + j) * 256]);                          \
        }                                                                       \
    }

#define CONSUME(BUF, KK)                                                        \
    {                                                                           \
        _Pragma("unroll")                                                       \
        for (int ks = 0; ks < 2; ++ks) {                                        \
            bf16x8 af[4];                                                       \
            _Pragma("unroll")                                                   \
            for (int ms = 0; ms < 4; ++ms)                                      \
                af[ms] = *(const bf16x8*)&co_bf[(size_t)(ms * 16 + li) * H + (KK) + ks * 32 + qu * 8]; \
            _Pragma("unroll")                                                   \
            for (int nt = 0; nt < 2; ++nt) {                                    \
                int row = w * 32 + nt * 16 + li;                                \
                int cc0 = ks * 8 + qu * 2;                                      \
                float4 x0 = *(const float4*)&Bs[BUF][row * 64 + ((cc0)     ^ (row & 15)) * 4]; \
                float4 x1 = *(const float4*)&Bs[BUF][row * 64 + ((cc0 + 1) ^ (row & 15)) * 4]; \
                bf16x8 bfr;                                                     \
                bfr[0] = (short)f2bf_rn(x0.x); bfr[1] = (short)f2bf_rn(x0.y);   \
                bfr[2] = (short)f2bf_rn(x0.z); bfr[3] = (short)f2bf_rn(x0.w);   \
                bfr[4] = (short)f2bf_rn(x1.x); bfr[5] = (short)f2bf_rn(x1.y);   \
                bfr[6] = (short)f2bf_rn(x1.z); bfr[7] = (short)f2bf_rn(x1.w);   \
                _Pragma("unroll")                                               \
                for (int ms = 0; ms < 4; ++ms)                                  \
                    acc[ms][nt] = __builtin_amdgcn_mfma_f32_16x16x32_bf16(      \
                        af[ms], bfr, acc[ms][nt], 0, 0, 0);                     \
            }                                                                   \
        }                                                                       \
    }

    STAGE(0, 0)
    STAGE(1, 64)
    for (int kt = 0; kt < 15; ++kt) {
        const int buf = kt & 1;
        wait_vm8();
        CONSUME(buf, kt * 64)
        if (kt + 2 < 16) { lds_war_guard(); STAGE(buf, (kt + 2) * 64) }
    }
    wait_vm0();
    CONSUME(1, 15 * 64)
#undef STAGE
#undef CONSUME

#pragma unroll
    for (int nt = 0; nt < 2; ++nt) {
        int v = v0 + w * 32 + nt * 16 + li;
        if (v < V) {
            float bov = bo[v];
#pragma unroll
            for (int ms = 0; ms < 4; ++ms)
#pragma unroll
                for (int j = 0; j < 4; ++j)
                    out[(size_t)(ms * 16 + qu * 4 + j) * V + v] = acc[ms][nt][j] + bov;
        }
    }
}

// ---------------------------------------------------------------------------
extern "C" void kernel_launch(void* const* d_in, const int* in_sizes, int n_in,
                              void* d_out, int out_size, void* d_ws, size_t ws_size,
                              hipStream_t stream) {
    (void)in_sizes; (void)n_in; (void)out_size; (void)ws_size;
    const int*   seq = (const int*)d_in[0];
    const float* h0  = (const float*)d_in[1];
    const float* enc = (const float*)d_in[2];
    const float* emb = (const float*)d_in[3];
    const float* Wih = (const float*)d_in[4];
    const float* Whh = (const float*)d_in[5];
    const float* bih = (const float*)d_in[6];
    const float* bhh = (const float*)d_in[7];
    const float* Wa  = (const float*)d_in[8];
    // d_in[9] = b_a: softmax over t is invariant to the per-b constant h·b_a -> unused
    const float* Wc  = (const float*)d_in[10];
    const float* bc  = (const float*)d_in[11];
    const float* Wo  = (const float*)d_in[12];
    const float* bo  = (const float*)d_in[13];

    float* out = (float*)d_out;
    float* hid = out + (size_t)B * V;

    float* ws   = (float*)d_ws;
    float* Pgi  = ws;                     // 786432
    float* Pgh  = Pgi + 786432;           // 786432
    float* Pu   = Pgh + 786432;           // 524288 (8 partials)
    float* Pm   = Pu + 524288;            // 1024
    float* Pl   = Pm + 1024;              // 1024
    float* Pc   = Pl + 1024;              // 1048576
    float* Pcg  = Pc + 1048576;           // 1048576 (16 partials)
    unsigned short* cat_bf = (unsigned short*)(Pcg + 1048576); // 131072 us
    unsigned short* co_bf  = cat_bf + 131072;                  // 65536 us

    k_gates<<<dim3(24, 4, 2), 256, 0, stream>>>(seq, emb, h0, Wih, Whh, Pgi, Pgh);
    k_gru<<<256, 256, 0, stream>>>(Pgi, Pgh, bih, bhh, h0, cat_bf, hid);
    k_mfma_wa<<<dim3(16, 8), 256, 0, stream>>>(cat_bf, Wa, Pu);
    k_flash<<<1024, 256, 0, stream>>>(Pu, enc, Pm, Pl, Pc);
    k_fcomb<<<64, 256, 0, stream>>>(Pm, Pl, Pc, cat_bf);
    k_mfma_bt<<<dim3(8, 16), 256, 0, stream>>>(cat_bf, 2 * H, Wc, 2 * H, Pcg, H, 128);
    k_co<<<256, 256, 0, stream>>>(Pcg, bc, co_bf);
    k_out_mfma<<<(V + 127) / 128, 256, 0, stream>>>(co_bf, Wo, bo, out);
}